// Round 1
// baseline (622.547 us; speedup 1.0000x reference)
//
#include <hip/hip_runtime.h>

#define HID 256
#define NFEAT 9
#define VOCAB 119
#define NLAYERS 4
#define NGRAPHS 256
#define BN_EPS 1e-5f

// ---------------- degree count (in-degree over dst) ----------------
__global__ void deg_kernel(const int* __restrict__ dst, int* __restrict__ degi, int E) {
    int i = blockIdx.x * blockDim.x + threadIdx.x;
    if (i < E) atomicAdd(&degi[dst[i]], 1);
}

__global__ void nrm_kernel(const int* __restrict__ degi, float* __restrict__ nrm, int N) {
    int i = blockIdx.x * blockDim.x + threadIdx.x;
    if (i < N) nrm[i] = rsqrtf(1.0f + (float)degi[i]);
}

// ---------------- single-block exclusive scan for CSR row_ptr ----------------
__global__ void scan_kernel(const int* __restrict__ degi, int* __restrict__ row_ptr, int N) {
    __shared__ int sdata[256];
    __shared__ int soff;
    int tid = threadIdx.x;
    if (tid == 0) soff = 0;
    __syncthreads();
    for (int base = 0; base < N; base += 256) {
        int v = (base + tid < N) ? degi[base + tid] : 0;
        sdata[tid] = v;
        __syncthreads();
        for (int s = 1; s < 256; s <<= 1) {
            int t = (tid >= s) ? sdata[tid - s] : 0;
            __syncthreads();
            sdata[tid] += t;
            __syncthreads();
        }
        if (base + tid < N) row_ptr[base + tid] = soff + sdata[tid] - v;  // exclusive
        __syncthreads();
        if (tid == 0) soff += sdata[255];
        __syncthreads();
    }
    if (tid == 0) row_ptr[N] = soff;
}

// ---------------- CSR fill (bucket src by dst) ----------------
__global__ void fill_kernel(const int* __restrict__ src, const int* __restrict__ dst,
                            const int* __restrict__ row_ptr, int* __restrict__ fill,
                            int* __restrict__ csr, int E) {
    int i = blockIdx.x * blockDim.x + threadIdx.x;
    if (i < E) {
        int d = dst[i];
        int pos = row_ptr[d] + atomicAdd(&fill[d], 1);
        csr[pos] = src[i];
    }
}

// ---------------- atom encoder: sum of 9 per-feature embeddings ----------------
__global__ __launch_bounds__(256) void embed_kernel(const int* __restrict__ x,
                                                    const float* __restrict__ emb,
                                                    float* __restrict__ h, int N) {
    int n = blockIdx.x;
    int c = threadIdx.x;
    __shared__ int xf[NFEAT];
    if (c < NFEAT) xf[c] = x[n * NFEAT + c];
    __syncthreads();
    float s = 0.f;
#pragma unroll
    for (int f = 0; f < NFEAT; ++f) s += emb[(f * VOCAB + xf[f]) * HID + c];
    h[n * HID + c] = s;
}

// ---------------- fp32 SGEMM: C[M,256] = A[M,256] * W[256,256] ----------------
// 64x64 tile, BK=16, 256 threads, each thread computes 4x4 (float4 acc)
__global__ __launch_bounds__(256) void gemm_kernel(const float* __restrict__ A,
                                                   const float* __restrict__ W,
                                                   float* __restrict__ C, int M) {
    __shared__ float As[16][68];  // [k][m], padded
    __shared__ float Bs[16][68];  // [k][n], padded
    int tid = threadIdx.x;
    int tx = tid & 15;
    int ty = tid >> 4;
    int rowBase = blockIdx.x * 64;
    int colBase = blockIdx.y * 64;
    float4 acc0 = make_float4(0, 0, 0, 0);
    float4 acc1 = make_float4(0, 0, 0, 0);
    float4 acc2 = make_float4(0, 0, 0, 0);
    float4 acc3 = make_float4(0, 0, 0, 0);

    int m = tid >> 2;
    int kf = (tid & 3) * 4;
    int kb = tid >> 4;
    int nb = (tid & 15) * 4;

    for (int kk = 0; kk < 256; kk += 16) {
        float4 av = make_float4(0, 0, 0, 0);
        int row = rowBase + m;
        if (row < M) av = *(const float4*)&A[row * 256 + kk + kf];
        float4 bv = *(const float4*)&W[(kk + kb) * 256 + colBase + nb];
        As[kf + 0][m] = av.x;
        As[kf + 1][m] = av.y;
        As[kf + 2][m] = av.z;
        As[kf + 3][m] = av.w;
        *(float4*)&Bs[kb][nb] = bv;
        __syncthreads();
#pragma unroll
        for (int k = 0; k < 16; ++k) {
            float4 a4 = *(const float4*)&As[k][ty * 4];
            float4 b4 = *(const float4*)&Bs[k][tx * 4];
            acc0.x += a4.x * b4.x; acc0.y += a4.x * b4.y; acc0.z += a4.x * b4.z; acc0.w += a4.x * b4.w;
            acc1.x += a4.y * b4.x; acc1.y += a4.y * b4.y; acc1.z += a4.y * b4.z; acc1.w += a4.y * b4.w;
            acc2.x += a4.z * b4.x; acc2.y += a4.z * b4.y; acc2.z += a4.z * b4.z; acc2.w += a4.z * b4.w;
            acc3.x += a4.w * b4.x; acc3.y += a4.w * b4.y; acc3.z += a4.w * b4.z; acc3.w += a4.w * b4.w;
        }
        __syncthreads();
    }
    int row0 = rowBase + ty * 4;
    int col = colBase + tx * 4;
    if (row0 + 0 < M) *(float4*)&C[(row0 + 0) * 256 + col] = acc0;
    if (row0 + 1 < M) *(float4*)&C[(row0 + 1) * 256 + col] = acc1;
    if (row0 + 2 < M) *(float4*)&C[(row0 + 2) * 256 + col] = acc2;
    if (row0 + 3 < M) *(float4*)&C[(row0 + 3) * 256 + col] = acc3;
}

// ---------------- GCN aggregate: one wave per node, CSR, no atomics ----------------
__global__ __launch_bounds__(64) void agg_kernel(const float* __restrict__ hw,
                                                 const int* __restrict__ row_ptr,
                                                 const int* __restrict__ csr,
                                                 const float* __restrict__ nrm,
                                                 const float* __restrict__ bias,
                                                 float* __restrict__ out, int N) {
    int n = blockIdx.x;
    int c = threadIdx.x * 4;
    float nd = nrm[n];
    int s = row_ptr[n], e = row_ptr[n + 1];
    float4 acc = make_float4(0, 0, 0, 0);
    for (int i = s; i < e; ++i) {
        int srcn = csr[i];
        float w = nrm[srcn] * nd;
        float4 v = *(const float4*)&hw[(size_t)srcn * HID + c];
        acc.x += w * v.x; acc.y += w * v.y; acc.z += w * v.z; acc.w += w * v.w;
    }
    float4 sv = *(const float4*)&hw[(size_t)n * HID + c];
    float sw = nd * nd;
    float4 bv = *(const float4*)&bias[c];
    acc.x += sw * sv.x + bv.x;
    acc.y += sw * sv.y + bv.y;
    acc.z += sw * sv.z + bv.z;
    acc.w += sw * sv.w + bv.w;
    *(float4*)&out[(size_t)n * HID + c] = acc;
}

// ---------------- per-channel sum / sumsq (BN stats) ----------------
__global__ __launch_bounds__(256) void colred_kernel(const float* __restrict__ a,
                                                     float* __restrict__ sums, int N) {
    int c = threadIdx.x;
    int nb = gridDim.x;
    int chunk = (N + nb - 1) / nb;
    int r0 = blockIdx.x * chunk;
    int r1 = min(r0 + chunk, N);
    float s = 0.f, s2 = 0.f;
    for (int r = r0; r < r1; ++r) {
        float v = a[(size_t)r * HID + c];
        s += v;
        s2 += v * v;
    }
    unsafeAtomicAdd(&sums[c], s);
    unsafeAtomicAdd(&sums[HID + c], s2);
}

// ---------------- BN apply + relu + residual ----------------
__global__ __launch_bounds__(256) void bn_kernel(const float* __restrict__ aggb,
                                                 const float* __restrict__ sums,
                                                 const float* __restrict__ gamma,
                                                 const float* __restrict__ beta,
                                                 const float* __restrict__ hold,
                                                 float* __restrict__ hnew, int N) {
    int idx = blockIdx.x * blockDim.x + threadIdx.x;
    if (idx >= N * HID) return;
    int c = idx & (HID - 1);
    float invN = 1.0f / (float)N;
    float mu = sums[c] * invN;
    float var = sums[HID + c] * invN - mu * mu;
    float sc = gamma[c] * rsqrtf(var + BN_EPS);
    float v = (aggb[idx] - mu) * sc + beta[c];
    v = fmaxf(v, 0.f);
    hnew[idx] = v + hold[idx];
}

// ---------------- global mean pool (sum + count) ----------------
__global__ __launch_bounds__(256) void pool_kernel(const float* __restrict__ h,
                                                   const int* __restrict__ batch,
                                                   float* __restrict__ gsum,
                                                   float* __restrict__ gcnt, int N) {
    int n = blockIdx.x;
    int c = threadIdx.x;
    int g = batch[n];
    unsafeAtomicAdd(&gsum[g * HID + c], h[(size_t)n * HID + c]);
    if (c == 0) unsafeAtomicAdd(&gcnt[g], 1.0f);
}

// ---------------- MLP head: one block per graph ----------------
__global__ __launch_bounds__(128) void mlp_kernel(const float* __restrict__ gsum,
                                                  const float* __restrict__ gcnt,
                                                  const float* __restrict__ W1,
                                                  const float* __restrict__ b1,
                                                  const float* __restrict__ W2,
                                                  const float* __restrict__ b2,
                                                  const float* __restrict__ W3,
                                                  const float* __restrict__ b3,
                                                  float* __restrict__ out) {
    __shared__ float gs[256];
    __shared__ float t1[128];
    __shared__ float t2[64];
    int gid = blockIdx.x;
    int tid = threadIdx.x;
    float inv = 1.0f / fmaxf(gcnt[gid], 1.0f);
    gs[tid] = gsum[gid * 256 + tid] * inv;
    gs[tid + 128] = gsum[gid * 256 + 128 + tid] * inv;
    __syncthreads();
    float acc = b1[tid];
    for (int k = 0; k < 256; ++k) acc += gs[k] * W1[k * 128 + tid];
    t1[tid] = fmaxf(acc, 0.f);
    __syncthreads();
    if (tid < 64) {
        float a2 = b2[tid];
        for (int k = 0; k < 128; ++k) a2 += t1[k] * W2[k * 64 + tid];
        t2[tid] = fmaxf(a2, 0.f);
    }
    __syncthreads();
    if (tid < 64) {
        float p = t2[tid] * W3[tid];
#pragma unroll
        for (int off = 32; off >= 1; off >>= 1) p += __shfl_down(p, off);
        if (tid == 0) out[gid] = p + b3[0];
    }
}

extern "C" void kernel_launch(void* const* d_in, const int* in_sizes, int n_in,
                              void* d_out, int out_size, void* d_ws, size_t ws_size,
                              hipStream_t stream) {
    const int* x      = (const int*)d_in[0];
    const int* ei     = (const int*)d_in[1];
    const int* batch  = (const int*)d_in[2];
    const float* emb  = (const float*)d_in[3];
    const float* W    = (const float*)d_in[4];
    const float* b    = (const float*)d_in[5];
    const float* gamma= (const float*)d_in[6];
    const float* beta = (const float*)d_in[7];
    const float* W1   = (const float*)d_in[8];
    const float* b1   = (const float*)d_in[9];
    const float* W2   = (const float*)d_in[10];
    const float* b2   = (const float*)d_in[11];
    const float* W3   = (const float*)d_in[12];
    const float* b3   = (const float*)d_in[13];
    float* out = (float*)d_out;

    int N = in_sizes[0] / NFEAT;
    int E = in_sizes[1] / 2;
    const int* srcp = ei;
    const int* dstp = ei + E;

    char* ws = (char*)d_ws;
    auto alloc = [&](size_t bytes) -> char* {
        char* p = ws;
        ws += (bytes + 255) & ~(size_t)255;
        return p;
    };
    int* degi     = (int*)alloc((size_t)N * 4);
    int* row_ptr  = (int*)alloc((size_t)(N + 1) * 4);
    int* fillc    = (int*)alloc((size_t)N * 4);
    float* nrm    = (float*)alloc((size_t)N * 4);
    int* csr      = (int*)alloc((size_t)E * 4);
    float* hA     = (float*)alloc((size_t)N * HID * 4);
    float* hB     = (float*)alloc((size_t)N * HID * 4);
    float* hw     = (float*)alloc((size_t)N * HID * 4);
    float* bnsums = (float*)alloc(2 * HID * 4);
    float* gsum   = (float*)alloc((size_t)NGRAPHS * HID * 4);
    float* gcnt   = (float*)alloc((size_t)NGRAPHS * 4);

    hipMemsetAsync(degi, 0, (size_t)N * 4, stream);
    hipMemsetAsync(fillc, 0, (size_t)N * 4, stream);
    hipMemsetAsync(gsum, 0, (size_t)NGRAPHS * HID * 4, stream);
    hipMemsetAsync(gcnt, 0, (size_t)NGRAPHS * 4, stream);

    deg_kernel<<<(E + 255) / 256, 256, 0, stream>>>(dstp, degi, E);
    nrm_kernel<<<(N + 255) / 256, 256, 0, stream>>>(degi, nrm, N);
    scan_kernel<<<1, 256, 0, stream>>>(degi, row_ptr, N);
    fill_kernel<<<(E + 255) / 256, 256, 0, stream>>>(srcp, dstp, row_ptr, fillc, csr, E);
    embed_kernel<<<N, 256, 0, stream>>>(x, emb, hA, N);

    float* hcur = hA;
    float* hoth = hB;
    for (int l = 0; l < NLAYERS; ++l) {
        dim3 ggrid((N + 63) / 64, 4);
        gemm_kernel<<<ggrid, 256, 0, stream>>>(hcur, W + (size_t)l * HID * HID, hw, N);
        agg_kernel<<<N, 64, 0, stream>>>(hw, row_ptr, csr, nrm, b + (size_t)l * HID, hoth, N);
        hipMemsetAsync(bnsums, 0, 2 * HID * 4, stream);
        colred_kernel<<<128, 256, 0, stream>>>(hoth, bnsums, N);
        bn_kernel<<<((size_t)N * HID + 255) / 256, 256, 0, stream>>>(
            hoth, bnsums, gamma + (size_t)l * HID, beta + (size_t)l * HID, hcur, hoth, N);
        float* t = hcur; hcur = hoth; hoth = t;
    }

    pool_kernel<<<N, 256, 0, stream>>>(hcur, batch, gsum, gcnt, N);
    mlp_kernel<<<NGRAPHS, 128, 0, stream>>>(gsum, gcnt, W1, b1, W2, b2, W3, b3, out);
}

// Round 2
// 524.203 us; speedup vs baseline: 1.1876x; 1.1876x over previous
//
#include <hip/hip_runtime.h>

#define HID 256
#define NFEAT 9
#define VOCAB 119
#define NLAYERS 4
#define NGRAPHS 256
#define BN_EPS 1e-5f

typedef short short8 __attribute__((ext_vector_type(8)));
typedef float floatx4 __attribute__((ext_vector_type(4)));

__device__ inline unsigned short f2bf(float f) {
    unsigned int u = __float_as_uint(f);
    unsigned int r = u + 0x7FFF + ((u >> 16) & 1);  // RNE
    return (unsigned short)(r >> 16);
}

// ---------------- degree count (in-degree over dst) ----------------
__global__ void deg_kernel(const int* __restrict__ dst, int* __restrict__ degi, int E) {
    int i = blockIdx.x * blockDim.x + threadIdx.x;
    if (i < E) atomicAdd(&degi[dst[i]], 1);
}

__global__ void nrm_kernel(const int* __restrict__ degi, float* __restrict__ nrm, int N) {
    int i = blockIdx.x * blockDim.x + threadIdx.x;
    if (i < N) nrm[i] = rsqrtf(1.0f + (float)degi[i]);
}

// ---------------- parallel exclusive scan (single block, 1024 thr) ----------------
__global__ __launch_bounds__(1024) void scan_kernel(const int* __restrict__ degi,
                                                    int* __restrict__ row_ptr, int N) {
    int tid = threadIdx.x;
    int ch = (N + 1023) >> 10;
    int i0 = tid * ch;
    int i1 = min(i0 + ch, N);
    if (i0 > N) i0 = N;
    int local = 0;
    for (int i = i0; i < i1; ++i) local += degi[i];
    int lane = tid & 63, wid = tid >> 6;
    int v = local;
#pragma unroll
    for (int off = 1; off < 64; off <<= 1) {
        int u = __shfl_up(v, off);
        if (lane >= off) v += u;
    }
    __shared__ int wsum[16];
    if (lane == 63) wsum[wid] = v;
    __syncthreads();
    if (tid < 16) {
        int w = wsum[tid];
#pragma unroll
        for (int off = 1; off < 16; off <<= 1) {
            int u = __shfl_up(w, off);
            if (tid >= off) w += u;
        }
        wsum[tid] = w;
    }
    __syncthreads();
    int base = (wid > 0 ? wsum[wid - 1] : 0) + (v - local);
    int run = base;
    for (int i = i0; i < i1; ++i) {
        row_ptr[i] = run;
        run += degi[i];
    }
    if (tid == 0) row_ptr[N] = wsum[15];
}

// ---------------- CSR fill (bucket src by dst) ----------------
__global__ void fill_kernel(const int* __restrict__ src, const int* __restrict__ dst,
                            const int* __restrict__ row_ptr, int* __restrict__ fill,
                            int* __restrict__ csr, int E) {
    int i = blockIdx.x * blockDim.x + threadIdx.x;
    if (i < E) {
        int d = dst[i];
        int pos = row_ptr[d] + atomicAdd(&fill[d], 1);
        csr[pos] = src[i];
    }
}

// ---------------- weight transpose + bf16 convert: Wt[l][n][k] ----------------
__global__ __launch_bounds__(256) void wcvt_kernel(const float* __restrict__ W,
                                                   unsigned short* __restrict__ Wt) {
    __shared__ float s[32][33];
    int l = blockIdx.z;
    int k0 = blockIdx.x * 32, n0 = blockIdx.y * 32;
    int c = threadIdx.x & 31, r8 = threadIdx.x >> 5;
    const float* Wl = W + (size_t)l * HID * HID;
    unsigned short* Wtl = Wt + (size_t)l * HID * HID;
#pragma unroll
    for (int p = 0; p < 4; ++p) {
        int r = r8 + p * 8;
        s[r][c] = Wl[(k0 + r) * HID + n0 + c];
    }
    __syncthreads();
#pragma unroll
    for (int p = 0; p < 4; ++p) {
        int r = r8 + p * 8;
        Wtl[(size_t)(n0 + r) * HID + k0 + c] = f2bf(s[c][r]);
    }
}

// ---------------- atom encoder: sum of 9 per-feature embeddings ----------------
__global__ __launch_bounds__(256) void embed_kernel(const int* __restrict__ x,
                                                    const float* __restrict__ emb,
                                                    float* __restrict__ h,
                                                    unsigned short* __restrict__ hb, int N) {
    int n = blockIdx.x;
    int c = threadIdx.x;
    __shared__ int xf[NFEAT];
    if (c < NFEAT) xf[c] = x[n * NFEAT + c];
    __syncthreads();
    float s = 0.f;
#pragma unroll
    for (int f = 0; f < NFEAT; ++f) s += emb[(size_t)(f * VOCAB + xf[f]) * HID + c];
    h[(size_t)n * HID + c] = s;
    hb[(size_t)n * HID + c] = f2bf(s);
}

// ---------------- bf16 MFMA GEMM: C[M,256] = A[M,256] x W[256,256] ----------------
// A bf16 [m][k]; Bt bf16 [n][k] (pre-transposed weights); C fp32.
// Block 256 thr = 4 waves; block tile 64x64; wave tile 32x32 = 2x2 mfma 16x16x32.
__global__ __launch_bounds__(256) void mfma_gemm(const unsigned short* __restrict__ A,
                                                 const unsigned short* __restrict__ Bt,
                                                 float* __restrict__ C, int M) {
    __shared__ unsigned short As[64][40];  // pad stride 40 shorts (80B) -> conflict-free b128
    __shared__ unsigned short Bs[64][40];
    int tid = threadIdx.x;
    int row0 = blockIdx.x * 64;
    int col0 = blockIdx.y * 64;
    int lrow = tid >> 2;       // 0..63 staging row
    int lkc = (tid & 3) * 8;   // 0,8,16,24 staging k-chunk
    int lane = tid & 63;
    int wid = tid >> 6;
    int wm = (wid & 1) * 32;
    int wn = (wid >> 1) * 32;
    int quad = lane >> 4;
    int ln = lane & 15;

    floatx4 acc00 = {0.f, 0.f, 0.f, 0.f};
    floatx4 acc01 = {0.f, 0.f, 0.f, 0.f};
    floatx4 acc10 = {0.f, 0.f, 0.f, 0.f};
    floatx4 acc11 = {0.f, 0.f, 0.f, 0.f};

    for (int kk = 0; kk < HID; kk += 32) {
        short8 av = {0, 0, 0, 0, 0, 0, 0, 0};
        int ar = row0 + lrow;
        if (ar < M) av = *(const short8*)&A[(size_t)ar * HID + kk + lkc];
        short8 bv = *(const short8*)&Bt[(size_t)(col0 + lrow) * HID + kk + lkc];
        *(short8*)&As[lrow][lkc] = av;
        *(short8*)&Bs[lrow][lkc] = bv;
        __syncthreads();
        // A/B fragment: [idx=lane&15][k=(lane>>4)*8+j]  (verified 16x16x32 layout)
        short8 a0 = *(const short8*)&As[wm + ln][quad * 8];
        short8 a1 = *(const short8*)&As[wm + 16 + ln][quad * 8];
        short8 b0 = *(const short8*)&Bs[wn + ln][quad * 8];
        short8 b1 = *(const short8*)&Bs[wn + 16 + ln][quad * 8];
        acc00 = __builtin_amdgcn_mfma_f32_16x16x32_bf16(a0, b0, acc00, 0, 0, 0);
        acc01 = __builtin_amdgcn_mfma_f32_16x16x32_bf16(a0, b1, acc01, 0, 0, 0);
        acc10 = __builtin_amdgcn_mfma_f32_16x16x32_bf16(a1, b0, acc10, 0, 0, 0);
        acc11 = __builtin_amdgcn_mfma_f32_16x16x32_bf16(a1, b1, acc11, 0, 0, 0);
        __syncthreads();
    }
    // C/D: col=lane&15, row=(lane>>4)*4+reg  (verified)
#pragma unroll
    for (int r = 0; r < 4; ++r) {
        int row = row0 + wm + quad * 4 + r;
        if (row < M) {
            C[(size_t)row * HID + col0 + wn + ln] = acc00[r];
            C[(size_t)row * HID + col0 + wn + 16 + ln] = acc01[r];
        }
        int row2 = row + 16;
        if (row2 < M) {
            C[(size_t)row2 * HID + col0 + wn + ln] = acc10[r];
            C[(size_t)row2 * HID + col0 + wn + 16 + ln] = acc11[r];
        }
    }
}

// ---------------- GCN aggregate: one wave per node, CSR, no atomics ----------------
__global__ __launch_bounds__(256) void agg_kernel(const float* __restrict__ hw,
                                                  const int* __restrict__ row_ptr,
                                                  const int* __restrict__ csr,
                                                  const float* __restrict__ nrm,
                                                  const float* __restrict__ bias,
                                                  float* __restrict__ out, int N) {
    int n = blockIdx.x * 4 + (threadIdx.x >> 6);
    if (n >= N) return;
    int c = (threadIdx.x & 63) * 4;
    float nd = nrm[n];
    int s = row_ptr[n], e = row_ptr[n + 1];
    float4 acc = make_float4(0, 0, 0, 0);
    for (int i = s; i < e; ++i) {
        int srcn = csr[i];
        float w = nrm[srcn] * nd;
        float4 v = *(const float4*)&hw[(size_t)srcn * HID + c];
        acc.x += w * v.x; acc.y += w * v.y; acc.z += w * v.z; acc.w += w * v.w;
    }
    float4 sv = *(const float4*)&hw[(size_t)n * HID + c];
    float sw = nd * nd;
    float4 bv = *(const float4*)&bias[c];
    acc.x += sw * sv.x + bv.x;
    acc.y += sw * sv.y + bv.y;
    acc.z += sw * sv.z + bv.z;
    acc.w += sw * sv.w + bv.w;
    *(float4*)&out[(size_t)n * HID + c] = acc;
}

// ---------------- per-channel sum / sumsq (BN stats) ----------------
__global__ __launch_bounds__(256) void colred_kernel(const float* __restrict__ a,
                                                     float* __restrict__ sums, int N) {
    int c = threadIdx.x;
    int nb = gridDim.x;
    int chunk = (N + nb - 1) / nb;
    int r0 = blockIdx.x * chunk;
    int r1 = min(r0 + chunk, N);
    float s = 0.f, s2 = 0.f;
    for (int r = r0; r < r1; ++r) {
        float v = a[(size_t)r * HID + c];
        s += v;
        s2 += v * v;
    }
    unsafeAtomicAdd(&sums[c], s);
    unsafeAtomicAdd(&sums[HID + c], s2);
}

// ---------------- BN apply + relu + residual (+ bf16 copy for next GEMM) ------
__global__ __launch_bounds__(256) void bn_kernel(const float* __restrict__ aggb,
                                                 const float* __restrict__ sums,
                                                 const float* __restrict__ gamma,
                                                 const float* __restrict__ beta,
                                                 const float* __restrict__ hold,
                                                 float* __restrict__ hnew,
                                                 unsigned short* __restrict__ hbnew, int N) {
    int idx = blockIdx.x * blockDim.x + threadIdx.x;
    if (idx >= N * HID) return;
    int c = idx & (HID - 1);
    float invN = 1.0f / (float)N;
    float mu = sums[c] * invN;
    float var = sums[HID + c] * invN - mu * mu;
    float sc = gamma[c] * rsqrtf(var + BN_EPS);
    float v = (aggb[idx] - mu) * sc + beta[c];
    v = fmaxf(v, 0.f);
    float o = v + hold[idx];
    hnew[idx] = o;
    hbnew[idx] = f2bf(o);
}

// ---------------- fused mean-pool (binary search on sorted batch) + MLP -------
__device__ inline int lower_bound_g(const int* __restrict__ a, int n, int key) {
    int lo = 0, hi = n;
    while (lo < hi) {
        int mid = (lo + hi) >> 1;
        if (a[mid] < key) lo = mid + 1; else hi = mid;
    }
    return lo;
}

__global__ __launch_bounds__(256) void pool_mlp_kernel(const float* __restrict__ h,
                                                       const int* __restrict__ batch, int N,
                                                       const float* __restrict__ W1,
                                                       const float* __restrict__ b1,
                                                       const float* __restrict__ W2,
                                                       const float* __restrict__ b2,
                                                       const float* __restrict__ W3,
                                                       const float* __restrict__ b3,
                                                       float* __restrict__ out) {
    int g = blockIdx.x, tid = threadIdx.x;
    int lo = lower_bound_g(batch, N, g);
    int hi = lower_bound_g(batch, N, g + 1);
    float s = 0.f;
    for (int i = lo; i < hi; ++i) s += h[(size_t)i * HID + tid];
    __shared__ float gs[256];
    __shared__ float t1[128];
    __shared__ float t2[64];
    float inv = 1.0f / fmaxf((float)(hi - lo), 1.0f);
    gs[tid] = s * inv;
    __syncthreads();
    if (tid < 128) {
        float a = b1[tid];
        for (int k = 0; k < 256; ++k) a += gs[k] * W1[k * 128 + tid];
        t1[tid] = fmaxf(a, 0.f);
    }
    __syncthreads();
    if (tid < 64) {
        float a = b2[tid];
        for (int k = 0; k < 128; ++k) a += t1[k] * W2[k * 64 + tid];
        t2[tid] = fmaxf(a, 0.f);
    }
    __syncthreads();
    if (tid < 64) {
        float p = t2[tid] * W3[tid];
#pragma unroll
        for (int off = 32; off >= 1; off >>= 1) p += __shfl_down(p, off);
        if (tid == 0) out[g] = p + b3[0];
    }
}

extern "C" void kernel_launch(void* const* d_in, const int* in_sizes, int n_in,
                              void* d_out, int out_size, void* d_ws, size_t ws_size,
                              hipStream_t stream) {
    const int* x      = (const int*)d_in[0];
    const int* ei     = (const int*)d_in[1];
    const int* batch  = (const int*)d_in[2];
    const float* emb  = (const float*)d_in[3];
    const float* W    = (const float*)d_in[4];
    const float* b    = (const float*)d_in[5];
    const float* gamma= (const float*)d_in[6];
    const float* beta = (const float*)d_in[7];
    const float* W1   = (const float*)d_in[8];
    const float* b1   = (const float*)d_in[9];
    const float* W2   = (const float*)d_in[10];
    const float* b2   = (const float*)d_in[11];
    const float* W3   = (const float*)d_in[12];
    const float* b3   = (const float*)d_in[13];
    float* out = (float*)d_out;

    int N = in_sizes[0] / NFEAT;
    int E = in_sizes[1] / 2;
    const int* srcp = ei;
    const int* dstp = ei + E;

    char* ws = (char*)d_ws;
    auto alloc = [&](size_t bytes) -> char* {
        char* p = ws;
        ws += (bytes + 255) & ~(size_t)255;
        return p;
    };
    int* degi     = (int*)alloc((size_t)N * 4);
    int* row_ptr  = (int*)alloc((size_t)(N + 1) * 4);
    int* fillc    = (int*)alloc((size_t)N * 4);
    float* nrm    = (float*)alloc((size_t)N * 4);
    int* csr      = (int*)alloc((size_t)E * 4);
    float* hA     = (float*)alloc((size_t)N * HID * 4);
    float* hB     = (float*)alloc((size_t)N * HID * 4);
    float* hw     = (float*)alloc((size_t)N * HID * 4);
    unsigned short* hbA = (unsigned short*)alloc((size_t)N * HID * 2);
    unsigned short* hbB = (unsigned short*)alloc((size_t)N * HID * 2);
    unsigned short* wt  = (unsigned short*)alloc((size_t)NLAYERS * HID * HID * 2);
    float* bnsums = (float*)alloc(2 * HID * 4);

    hipMemsetAsync(degi, 0, (size_t)N * 4, stream);
    hipMemsetAsync(fillc, 0, (size_t)N * 4, stream);

    deg_kernel<<<(E + 255) / 256, 256, 0, stream>>>(dstp, degi, E);
    nrm_kernel<<<(N + 255) / 256, 256, 0, stream>>>(degi, nrm, N);
    scan_kernel<<<1, 1024, 0, stream>>>(degi, row_ptr, N);
    fill_kernel<<<(E + 255) / 256, 256, 0, stream>>>(srcp, dstp, row_ptr, fillc, csr, E);
    wcvt_kernel<<<dim3(8, 8, NLAYERS), 256, 0, stream>>>(W, wt);
    embed_kernel<<<N, 256, 0, stream>>>(x, emb, hA, hbA, N);

    float* hcur = hA;
    float* hoth = hB;
    unsigned short* hbcur = hbA;
    unsigned short* hboth = hbB;
    for (int l = 0; l < NLAYERS; ++l) {
        dim3 ggrid((N + 63) / 64, 4);
        mfma_gemm<<<ggrid, 256, 0, stream>>>(hbcur, wt + (size_t)l * HID * HID, hw, N);
        agg_kernel<<<(N + 3) / 4, 256, 0, stream>>>(hw, row_ptr, csr, nrm,
                                                    b + (size_t)l * HID, hoth, N);
        hipMemsetAsync(bnsums, 0, 2 * HID * 4, stream);
        colred_kernel<<<128, 256, 0, stream>>>(hoth, bnsums, N);
        bn_kernel<<<((size_t)N * HID + 255) / 256, 256, 0, stream>>>(
            hoth, bnsums, gamma + (size_t)l * HID, beta + (size_t)l * HID,
            hcur, hoth, hboth, N);
        float* t = hcur; hcur = hoth; hoth = t;
        unsigned short* tb = hbcur; hbcur = hboth; hboth = tb;
    }

    pool_mlp_kernel<<<NGRAPHS, 256, 0, stream>>>(hcur, batch, N, W1, b1, W2, b2, W3, b3, out);
}

// Round 3
// 406.821 us; speedup vs baseline: 1.5303x; 1.2885x over previous
//
#include <hip/hip_runtime.h>

#define HID 256
#define NFEAT 9
#define VOCAB 119
#define NLAYERS 4
#define NGRAPHS 256
#define BN_EPS 1e-5f

typedef short short8 __attribute__((ext_vector_type(8)));
typedef float floatx4 __attribute__((ext_vector_type(4)));

__device__ inline unsigned short f2bf(float f) {
    unsigned int u = __float_as_uint(f);
    unsigned int r = u + 0x7FFF + ((u >> 16) & 1);  // RNE
    return (unsigned short)(r >> 16);
}
__device__ inline float bf2f(unsigned short u) {
    return __uint_as_float(((unsigned int)u) << 16);
}

// ---------------- degree count (in-degree over dst) ----------------
__global__ void deg_kernel(const int* __restrict__ dst, int* __restrict__ degi, int E) {
    int i = blockIdx.x * blockDim.x + threadIdx.x;
    if (i < E) atomicAdd(&degi[dst[i]], 1);
}

__global__ void nrm_kernel(const int* __restrict__ degi, float* __restrict__ nrm, int N) {
    int i = blockIdx.x * blockDim.x + threadIdx.x;
    if (i < N) nrm[i] = rsqrtf(1.0f + (float)degi[i]);
}

// ---------------- parallel exclusive scan (single block, 1024 thr) ----------------
__global__ __launch_bounds__(1024) void scan_kernel(const int* __restrict__ degi,
                                                    int* __restrict__ row_ptr, int N) {
    int tid = threadIdx.x;
    int ch = (N + 1023) >> 10;
    int i0 = tid * ch;
    int i1 = min(i0 + ch, N);
    if (i0 > N) i0 = N;
    int local = 0;
    for (int i = i0; i < i1; ++i) local += degi[i];
    int lane = tid & 63, wid = tid >> 6;
    int v = local;
#pragma unroll
    for (int off = 1; off < 64; off <<= 1) {
        int u = __shfl_up(v, off);
        if (lane >= off) v += u;
    }
    __shared__ int wsum[16];
    if (lane == 63) wsum[wid] = v;
    __syncthreads();
    if (tid < 16) {
        int w = wsum[tid];
#pragma unroll
        for (int off = 1; off < 16; off <<= 1) {
            int u = __shfl_up(w, off);
            if (tid >= off) w += u;
        }
        wsum[tid] = w;
    }
    __syncthreads();
    int base = (wid > 0 ? wsum[wid - 1] : 0) + (v - local);
    int run = base;
    for (int i = i0; i < i1; ++i) {
        row_ptr[i] = run;
        run += degi[i];
    }
    if (tid == 0) row_ptr[N] = wsum[15];
}

// ---------------- CSR fill (bucket src by dst) ----------------
__global__ void fill_kernel(const int* __restrict__ src, const int* __restrict__ dst,
                            const int* __restrict__ row_ptr, int* __restrict__ fill,
                            int* __restrict__ csr, int E) {
    int i = blockIdx.x * blockDim.x + threadIdx.x;
    if (i < E) {
        int d = dst[i];
        int pos = row_ptr[d] + atomicAdd(&fill[d], 1);
        csr[pos] = src[i];
    }
}

// ---------------- weight transpose + bf16 convert: Wt[l][n][k] ----------------
__global__ __launch_bounds__(256) void wcvt_kernel(const float* __restrict__ W,
                                                   unsigned short* __restrict__ Wt) {
    __shared__ float s[32][33];
    int l = blockIdx.z;
    int k0 = blockIdx.x * 32, n0 = blockIdx.y * 32;
    int c = threadIdx.x & 31, r8 = threadIdx.x >> 5;
    const float* Wl = W + (size_t)l * HID * HID;
    unsigned short* Wtl = Wt + (size_t)l * HID * HID;
#pragma unroll
    for (int p = 0; p < 4; ++p) {
        int r = r8 + p * 8;
        s[r][c] = Wl[(k0 + r) * HID + n0 + c];
    }
    __syncthreads();
#pragma unroll
    for (int p = 0; p < 4; ++p) {
        int r = r8 + p * 8;
        Wtl[(size_t)(n0 + r) * HID + k0 + c] = f2bf(s[c][r]);
    }
}

// ---------------- atom encoder: sum of 9 per-feature embeddings ----------------
__global__ __launch_bounds__(256) void embed_kernel(const int* __restrict__ x,
                                                    const float* __restrict__ emb,
                                                    float* __restrict__ h,
                                                    unsigned short* __restrict__ hb, int N) {
    int n = blockIdx.x;
    int c = threadIdx.x;
    __shared__ int xf[NFEAT];
    if (c < NFEAT) xf[c] = x[n * NFEAT + c];
    __syncthreads();
    float s = 0.f;
#pragma unroll
    for (int f = 0; f < NFEAT; ++f) s += emb[(size_t)(f * VOCAB + xf[f]) * HID + c];
    h[(size_t)n * HID + c] = s;
    hb[(size_t)n * HID + c] = f2bf(s);
}

// ---------------- GCN aggregate on bf16 h (before GEMM, by linearity) ---------
// one wave per node, 4 cols/lane (ushort4 = 8B loads), fp32 accumulate, bf16 out
__global__ __launch_bounds__(256) void agg_bf16_kernel(const unsigned short* __restrict__ hb,
                                                       const int* __restrict__ row_ptr,
                                                       const int* __restrict__ csr,
                                                       const float* __restrict__ nrm,
                                                       unsigned short* __restrict__ aggb, int N) {
    int n = blockIdx.x * 4 + (threadIdx.x >> 6);
    if (n >= N) return;
    int c = (threadIdx.x & 63) * 4;
    float nd = nrm[n];
    int s = row_ptr[n], e = row_ptr[n + 1];
    float4 acc = make_float4(0, 0, 0, 0);
    int i = s;
    for (; i + 1 < e; i += 2) {   // 2-edge unroll for more loads in flight
        int s0 = csr[i], s1 = csr[i + 1];
        float w0 = nrm[s0] * nd, w1 = nrm[s1] * nd;
        ushort4 u0 = *(const ushort4*)&hb[(size_t)s0 * HID + c];
        ushort4 u1 = *(const ushort4*)&hb[(size_t)s1 * HID + c];
        acc.x += w0 * bf2f(u0.x) + w1 * bf2f(u1.x);
        acc.y += w0 * bf2f(u0.y) + w1 * bf2f(u1.y);
        acc.z += w0 * bf2f(u0.z) + w1 * bf2f(u1.z);
        acc.w += w0 * bf2f(u0.w) + w1 * bf2f(u1.w);
    }
    if (i < e) {
        int s0 = csr[i];
        float w0 = nrm[s0] * nd;
        ushort4 u0 = *(const ushort4*)&hb[(size_t)s0 * HID + c];
        acc.x += w0 * bf2f(u0.x);
        acc.y += w0 * bf2f(u0.y);
        acc.z += w0 * bf2f(u0.z);
        acc.w += w0 * bf2f(u0.w);
    }
    ushort4 us = *(const ushort4*)&hb[(size_t)n * HID + c];
    float sw = nd * nd;
    acc.x += sw * bf2f(us.x);
    acc.y += sw * bf2f(us.y);
    acc.z += sw * bf2f(us.z);
    acc.w += sw * bf2f(us.w);
    ushort4 o;
    o.x = f2bf(acc.x); o.y = f2bf(acc.y); o.z = f2bf(acc.z); o.w = f2bf(acc.w);
    *(ushort4*)&aggb[(size_t)n * HID + c] = o;
}

// ---------------- bf16 MFMA GEMM + bias + fused BN column stats ----------------
// C[M,256] = A[M,256] x W[256,256] + b ; sums[c], sums[HID+c] += col sum/sumsq
__global__ __launch_bounds__(256) void mfma_gemm(const unsigned short* __restrict__ A,
                                                 const unsigned short* __restrict__ Bt,
                                                 const float* __restrict__ bias,
                                                 float* __restrict__ C,
                                                 float* __restrict__ sums, int M) {
    __shared__ unsigned short As[64][40];  // pad stride 40 shorts -> conflict-free b128
    __shared__ unsigned short Bs[64][40];
    __shared__ float lsum[64];
    __shared__ float lsq[64];
    int tid = threadIdx.x;
    int row0 = blockIdx.x * 64;
    int col0 = blockIdx.y * 64;
    int lrow = tid >> 2;
    int lkc = (tid & 3) * 8;
    int lane = tid & 63;
    int wid = tid >> 6;
    int wm = (wid & 1) * 32;
    int wn = (wid >> 1) * 32;
    int quad = lane >> 4;
    int ln = lane & 15;

    floatx4 acc00 = {0.f, 0.f, 0.f, 0.f};
    floatx4 acc01 = {0.f, 0.f, 0.f, 0.f};
    floatx4 acc10 = {0.f, 0.f, 0.f, 0.f};
    floatx4 acc11 = {0.f, 0.f, 0.f, 0.f};

    if (tid < 64) { lsum[tid] = 0.f; lsq[tid] = 0.f; }

    for (int kk = 0; kk < HID; kk += 32) {
        short8 av = {0, 0, 0, 0, 0, 0, 0, 0};
        int ar = row0 + lrow;
        if (ar < M) av = *(const short8*)&A[(size_t)ar * HID + kk + lkc];
        short8 bv = *(const short8*)&Bt[(size_t)(col0 + lrow) * HID + kk + lkc];
        *(short8*)&As[lrow][lkc] = av;
        *(short8*)&Bs[lrow][lkc] = bv;
        __syncthreads();
        short8 a0 = *(const short8*)&As[wm + ln][quad * 8];
        short8 a1 = *(const short8*)&As[wm + 16 + ln][quad * 8];
        short8 b0 = *(const short8*)&Bs[wn + ln][quad * 8];
        short8 b1 = *(const short8*)&Bs[wn + 16 + ln][quad * 8];
        acc00 = __builtin_amdgcn_mfma_f32_16x16x32_bf16(a0, b0, acc00, 0, 0, 0);
        acc01 = __builtin_amdgcn_mfma_f32_16x16x32_bf16(a0, b1, acc01, 0, 0, 0);
        acc10 = __builtin_amdgcn_mfma_f32_16x16x32_bf16(a1, b0, acc10, 0, 0, 0);
        acc11 = __builtin_amdgcn_mfma_f32_16x16x32_bf16(a1, b1, acc11, 0, 0, 0);
        __syncthreads();
    }
    // C/D: col=lane&15, row=(lane>>4)*4+reg  (verified)
    float bias0 = bias[col0 + wn + ln];
    float bias1 = bias[col0 + wn + 16 + ln];
    float p0 = 0.f, q0 = 0.f, p1 = 0.f, q1 = 0.f;
#pragma unroll
    for (int r = 0; r < 4; ++r) {
        int row = row0 + wm + quad * 4 + r;
        if (row < M) {
            float v0 = acc00[r] + bias0;
            float v1 = acc01[r] + bias1;
            C[(size_t)row * HID + col0 + wn + ln] = v0;
            C[(size_t)row * HID + col0 + wn + 16 + ln] = v1;
            p0 += v0; q0 += v0 * v0;
            p1 += v1; q1 += v1 * v1;
        }
        int row2 = row + 16;
        if (row2 < M) {
            float v0 = acc10[r] + bias0;
            float v1 = acc11[r] + bias1;
            C[(size_t)row2 * HID + col0 + wn + ln] = v0;
            C[(size_t)row2 * HID + col0 + wn + 16 + ln] = v1;
            p0 += v0; q0 += v0 * v0;
            p1 += v1; q1 += v1 * v1;
        }
    }
    atomicAdd(&lsum[wn + ln], p0);
    atomicAdd(&lsq[wn + ln], q0);
    atomicAdd(&lsum[wn + 16 + ln], p1);
    atomicAdd(&lsq[wn + 16 + ln], q1);
    __syncthreads();
    if (tid < 64) {
        unsafeAtomicAdd(&sums[col0 + tid], lsum[tid]);
        unsafeAtomicAdd(&sums[HID + col0 + tid], lsq[tid]);
    }
}

// ---------------- BN apply + relu + residual (+ bf16 copy for next GEMM) ------
__global__ __launch_bounds__(256) void bn_kernel(const float* __restrict__ aggb,
                                                 const float* __restrict__ sums,
                                                 const float* __restrict__ gamma,
                                                 const float* __restrict__ beta,
                                                 const float* __restrict__ hold,
                                                 float* __restrict__ hnew,
                                                 unsigned short* __restrict__ hbnew, int N) {
    int idx = blockIdx.x * blockDim.x + threadIdx.x;
    if (idx >= N * HID) return;
    int c = idx & (HID - 1);
    float invN = 1.0f / (float)N;
    float mu = sums[c] * invN;
    float var = sums[HID + c] * invN - mu * mu;
    float sc = gamma[c] * rsqrtf(var + BN_EPS);
    float v = (aggb[idx] - mu) * sc + beta[c];
    v = fmaxf(v, 0.f);
    float o = v + hold[idx];
    hnew[idx] = o;
    hbnew[idx] = f2bf(o);
}

// ---------------- fused mean-pool (binary search on sorted batch) + MLP -------
__device__ inline int lower_bound_g(const int* __restrict__ a, int n, int key) {
    int lo = 0, hi = n;
    while (lo < hi) {
        int mid = (lo + hi) >> 1;
        if (a[mid] < key) lo = mid + 1; else hi = mid;
    }
    return lo;
}

__global__ __launch_bounds__(256) void pool_mlp_kernel(const float* __restrict__ h,
                                                       const int* __restrict__ batch, int N,
                                                       const float* __restrict__ W1,
                                                       const float* __restrict__ b1,
                                                       const float* __restrict__ W2,
                                                       const float* __restrict__ b2,
                                                       const float* __restrict__ W3,
                                                       const float* __restrict__ b3,
                                                       float* __restrict__ out) {
    int g = blockIdx.x, tid = threadIdx.x;
    int lo = lower_bound_g(batch, N, g);
    int hi = lower_bound_g(batch, N, g + 1);
    float s = 0.f;
    for (int i = lo; i < hi; ++i) s += h[(size_t)i * HID + tid];
    __shared__ float gs[256];
    __shared__ float t1[128];
    __shared__ float t2[64];
    float inv = 1.0f / fmaxf((float)(hi - lo), 1.0f);
    gs[tid] = s * inv;
    __syncthreads();
    if (tid < 128) {
        float a = b1[tid];
        for (int k = 0; k < 256; ++k) a += gs[k] * W1[k * 128 + tid];
        t1[tid] = fmaxf(a, 0.f);
    }
    __syncthreads();
    if (tid < 64) {
        float a = b2[tid];
        for (int k = 0; k < 128; ++k) a += t1[k] * W2[k * 64 + tid];
        t2[tid] = fmaxf(a, 0.f);
    }
    __syncthreads();
    if (tid < 64) {
        float p = t2[tid] * W3[tid];
#pragma unroll
        for (int off = 32; off >= 1; off >>= 1) p += __shfl_down(p, off);
        if (tid == 0) out[g] = p + b3[0];
    }
}

extern "C" void kernel_launch(void* const* d_in, const int* in_sizes, int n_in,
                              void* d_out, int out_size, void* d_ws, size_t ws_size,
                              hipStream_t stream) {
    const int* x      = (const int*)d_in[0];
    const int* ei     = (const int*)d_in[1];
    const int* batch  = (const int*)d_in[2];
    const float* emb  = (const float*)d_in[3];
    const float* W    = (const float*)d_in[4];
    const float* b    = (const float*)d_in[5];
    const float* gamma= (const float*)d_in[6];
    const float* beta = (const float*)d_in[7];
    const float* W1   = (const float*)d_in[8];
    const float* b1   = (const float*)d_in[9];
    const float* W2   = (const float*)d_in[10];
    const float* b2   = (const float*)d_in[11];
    const float* W3   = (const float*)d_in[12];
    const float* b3   = (const float*)d_in[13];
    float* out = (float*)d_out;

    int N = in_sizes[0] / NFEAT;
    int E = in_sizes[1] / 2;
    const int* srcp = ei;
    const int* dstp = ei + E;

    char* ws = (char*)d_ws;
    auto alloc = [&](size_t bytes) -> char* {
        char* p = ws;
        ws += (bytes + 255) & ~(size_t)255;
        return p;
    };
    int* degi     = (int*)alloc((size_t)N * 4);
    int* row_ptr  = (int*)alloc((size_t)(N + 1) * 4);
    int* fillc    = (int*)alloc((size_t)N * 4);
    float* nrm    = (float*)alloc((size_t)N * 4);
    int* csr      = (int*)alloc((size_t)E * 4);
    float* hA     = (float*)alloc((size_t)N * HID * 4);
    float* hB     = (float*)alloc((size_t)N * HID * 4);
    float* hw     = (float*)alloc((size_t)N * HID * 4);
    unsigned short* hbA  = (unsigned short*)alloc((size_t)N * HID * 2);
    unsigned short* hbB  = (unsigned short*)alloc((size_t)N * HID * 2);
    unsigned short* aggb = (unsigned short*)alloc((size_t)N * HID * 2);
    unsigned short* wt   = (unsigned short*)alloc((size_t)NLAYERS * HID * HID * 2);
    float* bnsums = (float*)alloc(2 * HID * 4);

    hipMemsetAsync(degi, 0, (size_t)N * 4, stream);
    hipMemsetAsync(fillc, 0, (size_t)N * 4, stream);

    deg_kernel<<<(E + 255) / 256, 256, 0, stream>>>(dstp, degi, E);
    nrm_kernel<<<(N + 255) / 256, 256, 0, stream>>>(degi, nrm, N);
    scan_kernel<<<1, 1024, 0, stream>>>(degi, row_ptr, N);
    fill_kernel<<<(E + 255) / 256, 256, 0, stream>>>(srcp, dstp, row_ptr, fillc, csr, E);
    wcvt_kernel<<<dim3(8, 8, NLAYERS), 256, 0, stream>>>(W, wt);
    embed_kernel<<<N, 256, 0, stream>>>(x, emb, hA, hbA, N);

    float* hcur = hA;
    float* hoth = hB;
    unsigned short* hbcur = hbA;
    unsigned short* hboth = hbB;
    for (int l = 0; l < NLAYERS; ++l) {
        agg_bf16_kernel<<<(N + 3) / 4, 256, 0, stream>>>(hbcur, row_ptr, csr, nrm, aggb, N);
        hipMemsetAsync(bnsums, 0, 2 * HID * 4, stream);
        dim3 ggrid((N + 63) / 64, 4);
        mfma_gemm<<<ggrid, 256, 0, stream>>>(aggb, wt + (size_t)l * HID * HID,
                                             b + (size_t)l * HID, hw, bnsums, N);
        bn_kernel<<<((size_t)N * HID + 255) / 256, 256, 0, stream>>>(
            hw, bnsums, gamma + (size_t)l * HID, beta + (size_t)l * HID,
            hcur, hoth, hboth, N);
        float* t = hcur; hcur = hoth; hoth = t;
        unsigned short* tb = hbcur; hbcur = hboth; hboth = tb;
    }

    pool_mlp_kernel<<<NGRAPHS, 256, 0, stream>>>(hcur, batch, N, W1, b1, W2, b2, W3, b3, out);
}